// Round 1
// baseline (294.438 us; speedup 1.0000x reference)
//
#include <hip/hip_runtime.h>
#include <math.h>

#define CN 128
#define SN 56
#define TB_R 61        // padded rows: -2..58
#define TB_S 61        // padded col stride (odd -> no 2^k bank aliasing)
#define LOG2E 1.44269504088896340736f

// Kernel 1: materialize the gaussian bank g[c][u][36] into workspace.
__global__ void gauss_bank_kernel(const float* __restrict__ theta,
                                  const float* __restrict__ p,
                                  const float* __restrict__ sig,
                                  const float* __restrict__ a,
                                  float* __restrict__ g) {
    int idx = blockIdx.x * blockDim.x + threadIdx.x;   // (c,u) pair
    if (idx >= CN * CN) return;
    float th = theta[idx];
    float pp = p[idx];
    float ss = sig[idx];
    float aa = a[idx];
    float ct = cosf(th), st = sinf(th);
    float ip2 = 1.0f / (pp * pp);
    float is2 = 1.0f / (ss * ss);
    float amp = aa / (2.0f * 3.14159265358979323846f * pp * ss);
    float* go = g + (size_t)idx * 36;
    #pragma unroll
    for (int ky = 0; ky < 6; ++ky) {
        float xv = -3.0f + 1.2f * ky;
        #pragma unroll
        for (int kx = 0; kx < 6; ++kx) {
            float yv = -3.0f + 1.2f * kx;
            float xr = xv * ct + yv * st;
            float yr = -xv * st + yv * ct;
            float e = -0.5f * (xr * xr * ip2 + yr * yr * is2);
            go[ky * 6 + kx] = amp * __builtin_amdgcn_exp2f(e * LOG2E);
        }
    }
}

// Kernel 2: one workgroup per (b,c). 448 threads = 56 rows x 8 threads,
// each thread owns 7 consecutive pixels in its row.
__global__ __launch_bounds__(448) void divnorm_kernel(
        const float* __restrict__ x, const float* __restrict__ g,
        const float* __restrict__ nI, const float* __restrict__ nU,
        const float* __restrict__ bias, float* __restrict__ out) {
    __shared__ float tb[2][TB_R * TB_S];

    const int blk = blockIdx.x;
    const int b = blk >> 7;
    const int c = blk & 127;
    const int tid = threadIdx.x;
    const int row = tid >> 3;          // 0..55
    const int x0 = (tid & 7) * 7;      // 0,7,...,49

    // Zero both buffers (establishes the zero halo; interior overwritten each u).
    for (int i = tid; i < 2 * TB_R * TB_S; i += 448) ((float*)tb)[i] = 0.0f;

    const float* xrow = x + ((size_t)(b * CN + c)) * (SN * SN) + row * SN + x0;
    float L2[7], acc[7];
    #pragma unroll
    for (int q = 0; q < 7; ++q) {
        L2[q] = __builtin_amdgcn_logf(xrow[q]);   // log2(x); x=0 -> -inf -> t=0 (correct)
        acc[q] = 0.0f;
    }

    const float* nIrow = nI + c * CN;             // wave-uniform scalar loads
    const float* gbase = g + (size_t)c * CN * 36;

    // Stage t for u=0 into buffer 0. Pixel (row, x) -> tb[row+2][x+2].
    {
        float nn = nIrow[0];
        float* dst = &tb[0][(row + 2) * TB_S + x0 + 2];
        #pragma unroll
        for (int q = 0; q < 7; ++q) dst[q] = __builtin_amdgcn_exp2f(nn * L2[q]);
    }
    __syncthreads();

    int cur = 0;
    for (int u = 0; u < CN; ++u) {
        const int nxt = cur ^ 1;
        // Stage next u's t into the other buffer (no race: disjoint from reads).
        if (u + 1 < CN) {
            float nn = nIrow[u + 1];
            float* dst = &tb[nxt][(row + 2) * TB_S + x0 + 2];
            #pragma unroll
            for (int q = 0; q < 7; ++q) dst[q] = __builtin_amdgcn_exp2f(nn * L2[q]);
        }
        // 6x6 conv: tap (y+dy-2, x+dx-2) lives at tb[row+dy][x0 + q + dx].
        const float* gw = gbase + u * 36;         // wave-uniform -> s_load
        const float* tbc = tb[cur];
        #pragma unroll
        for (int dy = 0; dy < 6; ++dy) {
            const float* trow = &tbc[(row + dy) * TB_S + x0];
            const float w0 = gw[dy * 6 + 0];
            const float w1 = gw[dy * 6 + 1];
            const float w2 = gw[dy * 6 + 2];
            const float w3 = gw[dy * 6 + 3];
            const float w4 = gw[dy * 6 + 4];
            const float w5 = gw[dy * 6 + 5];
            float win[12];
            #pragma unroll
            for (int k = 0; k < 12; ++k) win[k] = trow[k];
            #pragma unroll
            for (int q = 0; q < 7; ++q) {
                float s = acc[q];
                s = fmaf(win[q + 0], w0, s);
                s = fmaf(win[q + 1], w1, s);
                s = fmaf(win[q + 2], w2, s);
                s = fmaf(win[q + 3], w3, s);
                s = fmaf(win[q + 4], w4, s);
                s = fmaf(win[q + 5], w5, s);
                acc[q] = s;
            }
        }
        __syncthreads();
        cur = nxt;
    }

    const float nUc = nU[c];
    const float bc = bias[c];
    const float bn = __builtin_amdgcn_exp2f(nUc * __builtin_amdgcn_logf(bc));
    float* op = out + ((size_t)(b * CN + c)) * (SN * SN) + row * SN + x0;
    #pragma unroll
    for (int q = 0; q < 7; ++q) {
        float num = __builtin_amdgcn_exp2f(nUc * L2[q]);
        op[q] = num / (bn + acc[q]);
    }
}

extern "C" void kernel_launch(void* const* d_in, const int* in_sizes, int n_in,
                              void* d_out, int out_size, void* d_ws, size_t ws_size,
                              hipStream_t stream) {
    const float* x     = (const float*)d_in[0];
    const float* theta = (const float*)d_in[1];
    const float* p     = (const float*)d_in[2];
    const float* sig   = (const float*)d_in[3];
    const float* a     = (const float*)d_in[4];
    const float* nI    = (const float*)d_in[5];
    const float* nU    = (const float*)d_in[6];
    const float* bias  = (const float*)d_in[7];
    float* out = (float*)d_out;
    float* g   = (float*)d_ws;   // 128*128*36 floats = 2.36 MB

    hipLaunchKernelGGL(gauss_bank_kernel, dim3((CN * CN + 255) / 256), dim3(256), 0, stream,
                       theta, p, sig, a, g);
    hipLaunchKernelGGL(divnorm_kernel, dim3(2 * CN), dim3(448), 0, stream,
                       x, g, nI, nU, bias, out);
}

// Round 2
// 183.165 us; speedup vs baseline: 1.6075x; 1.6075x over previous
//
#include <hip/hip_runtime.h>
#include <math.h>

#define CN 128
#define SN 56
#define NTAP 36
#define TSTR 68                 // LDS row stride (68 % 32 == 4 -> conflict-free pattern)
#define LDS_FLOATS (61 * TSTR + 8)
#define USPLIT 8
#define UCHUNK 16
#define LOG2E 1.44269504088896340736f

// ---------------- Kernel 1: gaussian bank, one thread per (pair, tap) ----------------
__global__ void gauss_bank_kernel(const float* __restrict__ theta,
                                  const float* __restrict__ p,
                                  const float* __restrict__ sig,
                                  const float* __restrict__ a,
                                  float* __restrict__ g) {
    int idx = blockIdx.x * blockDim.x + threadIdx.x;
    if (idx >= CN * CN * NTAP) return;
    int pair = idx / NTAP;
    int tap  = idx - pair * NTAP;
    int ky = tap / 6, kx = tap - ky * 6;
    float th = theta[pair], pp = p[pair], ss = sig[pair], aa = a[pair];
    float ct = cosf(th), st = sinf(th);
    float xv = -3.0f + 1.2f * ky;
    float yv = -3.0f + 1.2f * kx;
    float xr = xv * ct + yv * st;
    float yr = -xv * st + yv * ct;
    float e = -0.5f * (xr * xr / (pp * pp) + yr * yr / (ss * ss));
    float amp = aa / (2.0f * 3.14159265358979323846f * pp * ss);
    g[idx] = amp * __builtin_amdgcn_exp2f(e * LOG2E);
}

// ---------------- Kernel 2: partial denominators ----------------
// Grid: 2048 blocks = (b in 2) x (c in 128) x (u-chunk s in 8). 64 threads = 1 wave.
// Thread (rc = tid>>3, j = tid&7) computes out rows 7rc..7rc+6, cols 8j..8j+7
// (strip j=7 computes garbage for cols 56..63, never stored).
// Thread t (t<56) stages pixel row t each u: t = exp2(nI * log2(x)), log2 in regs.
__global__ __launch_bounds__(64, 2) void divnorm_kernel(
        const float* __restrict__ x, const float* __restrict__ g,
        const float* __restrict__ nI, float* __restrict__ part) {
    __shared__ float tb[LDS_FLOATS];

    const int bid = blockIdx.x;
    const int s   = bid & 7;
    const int c   = (bid >> 3) & 127;
    const int b   = bid >> 10;
    const int tid = threadIdx.x;
    const int j   = tid & 7;
    const int rc  = tid >> 3;

    // Zero everything once: establishes zero halo (rows 0,1,58..60; cols 0..3,60..67+pad).
    for (int i = tid; i < LDS_FLOATS; i += 64) tb[i] = 0.0f;

    // Each thread t<56 owns pixel row t for staging; keep log2(x[row]) in 56 VGPRs.
    float L[SN];
    if (tid < SN) {
        const float4* xr = (const float4*)(x + ((size_t)(b * CN + c)) * (SN * SN) + tid * SN);
        #pragma unroll
        for (int m = 0; m < 14; ++m) {
            float4 v = xr[m];
            L[4 * m + 0] = __builtin_amdgcn_logf(v.x);
            L[4 * m + 1] = __builtin_amdgcn_logf(v.y);
            L[4 * m + 2] = __builtin_amdgcn_logf(v.z);
            L[4 * m + 3] = __builtin_amdgcn_logf(v.w);
        }
    }
    __syncthreads();

    const float* nIrow = nI + c * CN;                    // wave-uniform
    const float* gc    = g + (size_t)c * CN * NTAP;

    float acc[7][8];
    #pragma unroll
    for (int yy = 0; yy < 7; ++yy)
        #pragma unroll
        for (int q = 0; q < 8; ++q) acc[yy][q] = 0.0f;

    #pragma unroll 1
    for (int uu = 0; uu < UCHUNK; ++uu) {
        const int u = s * UCHUNK + uu;

        // Stage t_u: pixel (row, cc) -> tb[(row+2)*TSTR + cc + 4], 14 aligned b128 writes.
        if (tid < SN) {
            const float nn = nIrow[u];
            float4* dst = (float4*)&tb[(tid + 2) * TSTR + 4];
            #pragma unroll
            for (int m = 0; m < 14; ++m) {
                float4 t4;
                t4.x = __builtin_amdgcn_exp2f(nn * L[4 * m + 0]);
                t4.y = __builtin_amdgcn_exp2f(nn * L[4 * m + 1]);
                t4.z = __builtin_amdgcn_exp2f(nn * L[4 * m + 2]);
                t4.w = __builtin_amdgcn_exp2f(nn * L[4 * m + 3]);
                dst[m] = t4;
            }
        }
        __syncthreads();

        const float* gw = gc + u * NTAP;                 // wave-uniform -> s_load
        float gg[NTAP];
        #pragma unroll
        for (int i2 = 0; i2 < NTAP; ++i2) gg[i2] = gw[i2];

        // 12 input rows feed 7 output rows. Window: out col 8j+q, tap kx ->
        // stored col 8j + (q+kx+2); aligned 16-float read at 8j (pad=2, static).
        #pragma unroll
        for (int t = 0; t < 12; ++t) {
            const float4* p4 = (const float4*)&tb[(7 * rc + t) * TSTR + 8 * j];
            float4 a0 = p4[0], a1 = p4[1], a2 = p4[2], a3 = p4[3];
            float w[16] = {a0.x, a0.y, a0.z, a0.w, a1.x, a1.y, a1.z, a1.w,
                           a2.x, a2.y, a2.z, a2.w, a3.x, a3.y, a3.z, a3.w};
            #pragma unroll
            for (int yy = 0; yy < 7; ++yy) {
                const int dy = t - yy;
                if (dy >= 0 && dy < 6) {
                    #pragma unroll
                    for (int q = 0; q < 8; ++q) {
                        float sv = acc[yy][q];
                        sv = fmaf(w[2 + q + 0], gg[dy * 6 + 0], sv);
                        sv = fmaf(w[2 + q + 1], gg[dy * 6 + 1], sv);
                        sv = fmaf(w[2 + q + 2], gg[dy * 6 + 2], sv);
                        sv = fmaf(w[2 + q + 3], gg[dy * 6 + 3], sv);
                        sv = fmaf(w[2 + q + 4], gg[dy * 6 + 4], sv);
                        sv = fmaf(w[2 + q + 5], gg[dy * 6 + 5], sv);
                        acc[yy][q] = sv;
                    }
                }
            }
        }
        __syncthreads();   // conv reads done before next u's staging overwrites
    }

    // Store partial denominator: part[s][b][c][y][x], strip j=7 dropped.
    if (j < 7) {
        float* pb = part + ((size_t)((s * 2 + b) * CN + c)) * (SN * SN);
        #pragma unroll
        for (int yy = 0; yy < 7; ++yy) {
            const int y = 7 * rc + yy;
            float4 v0 = make_float4(acc[yy][0], acc[yy][1], acc[yy][2], acc[yy][3]);
            float4 v1 = make_float4(acc[yy][4], acc[yy][5], acc[yy][6], acc[yy][7]);
            ((float4*)(pb + y * SN + 8 * j))[0] = v0;
            ((float4*)(pb + y * SN + 8 * j + 4))[0] = v1;
        }
    }
}

// ---------------- Kernel 3: combine partials + numerator ----------------
// part index for chunk s collapses to s*802816 + gid.
__global__ void combine_kernel(const float* __restrict__ x,
                               const float* __restrict__ part,
                               const float* __restrict__ nU,
                               const float* __restrict__ bias,
                               float* __restrict__ out) {
    const int gid = blockIdx.x * blockDim.x + threadIdx.x;   // < 2*128*3136
    const int bc  = gid / (SN * SN);
    const int c   = bc & 127;
    const float nu = nU[c];
    float d = __builtin_amdgcn_exp2f(nu * __builtin_amdgcn_logf(bias[c]));
    #pragma unroll
    for (int s = 0; s < USPLIT; ++s)
        d += part[(size_t)s * (2 * CN * SN * SN) + gid];
    const float num = __builtin_amdgcn_exp2f(nu * __builtin_amdgcn_logf(x[gid]));
    out[gid] = num / d;
}

extern "C" void kernel_launch(void* const* d_in, const int* in_sizes, int n_in,
                              void* d_out, int out_size, void* d_ws, size_t ws_size,
                              hipStream_t stream) {
    const float* x     = (const float*)d_in[0];
    const float* theta = (const float*)d_in[1];
    const float* p     = (const float*)d_in[2];
    const float* sig   = (const float*)d_in[3];
    const float* a     = (const float*)d_in[4];
    const float* nI    = (const float*)d_in[5];
    const float* nU    = (const float*)d_in[6];
    const float* bias  = (const float*)d_in[7];
    float* out = (float*)d_out;

    float* g    = (float*)d_ws;                          // 128*128*36 = 2.36 MB
    float* part = g + (size_t)CN * CN * NTAP;            // 8*2*128*3136*4 = 25.7 MB

    hipLaunchKernelGGL(gauss_bank_kernel,
                       dim3((CN * CN * NTAP + 255) / 256), dim3(256), 0, stream,
                       theta, p, sig, a, g);
    hipLaunchKernelGGL(divnorm_kernel, dim3(2 * CN * USPLIT), dim3(64), 0, stream,
                       x, g, nI, part);
    hipLaunchKernelGGL(combine_kernel, dim3(2 * CN * SN * SN / 256), dim3(256), 0, stream,
                       x, part, nU, bias, out);
}

// Round 3
// 137.035 us; speedup vs baseline: 2.1486x; 1.3366x over previous
//
#include <hip/hip_runtime.h>
#include <math.h>

#define CN 128
#define SN 56
#define PROWS 19               // band P rows: r0-2 .. r0+16
#define PCOLS 33               // block P cols: c0-2 .. c0+30
#define PTAP 36
#define PSTRIDE (PCOLS*PTAP)   // 1188 ushorts per P row
#define PSIZE (PROWS*PSTRIDE)  // 22572 ushorts = 45144 B
#define GTS 136                // Gt row stride (ushorts); 272B = 17 quads -> good bank spread
#define NPX (PROWS*PCOLS)      // 627 valid flattened px per band

typedef float  fr4 __attribute__((ext_vector_type(4)));
typedef short  sh8 __attribute__((ext_vector_type(8)));

__device__ __forceinline__ unsigned short f2bf(float f) {
    unsigned u = __float_as_uint(f);
    u += 0x7FFFu + ((u >> 16) & 1u);          // RNE
    return (unsigned short)(u >> 16);
}
__device__ __forceinline__ float bf2f(unsigned short s) {
    return __uint_as_float(((unsigned)s) << 16);
}

// One block per (b, c, row-half h, col-half w). 256 threads = 4 waves.
// Per 14-row band: GEMM P[627 px, 36 taps] = T[px,128u] * G[128u,36taps] via
// mfma_f32_16x16x32_bf16 (A-frags computed in-register: t = exp2(nI*log2 x)),
// then 6x6 tap-stencil gather from P (LDS bf16) -> out.
__global__ __launch_bounds__(256, 2) void divnorm_mfma(
        const float* __restrict__ x, const float* __restrict__ theta,
        const float* __restrict__ pP, const float* __restrict__ sig,
        const float* __restrict__ aA, const float* __restrict__ nI,
        const float* __restrict__ nU, const float* __restrict__ bias,
        float* __restrict__ out)
{
    __shared__ alignas(16) unsigned short Pl[PSIZE];
    __shared__ alignas(16) unsigned short Gt[48 * GTS];   // [tap(pad48)][u]

    const int bid = blockIdx.x;
    const int w   = bid & 1;
    const int h   = (bid >> 1) & 1;
    const int c   = (bid >> 2) & 127;
    const int b   = bid >> 9;
    const int tid = threadIdx.x;
    const int lane = tid & 63;
    const int wv   = tid >> 6;
    const int l15  = lane & 15;
    const int lg   = lane >> 4;

    // Zero Gt pad rows 36..47 (read by B-frags for pad-N; outputs masked anyway).
    for (int i = tid; i < 12 * GTS; i += 256) Gt[36 * GTS + i] = 0;

    // Gaussian bank inline: G[u, tap] -> Gt[tap][u] bf16.
    for (int idx = tid; idx < CN * 36; idx += 256) {
        int u  = idx / 36;
        int tap = idx - u * 36;
        int ky = tap / 6;
        int kx = tap - ky * 6;
        int pr = c * CN + u;
        float th = theta[pr], pv = pP[pr], sv = sig[pr], av = aA[pr];
        float ct = __cosf(th), st = __sinf(th);
        float xv = -3.0f + 1.2f * ky;
        float yv = -3.0f + 1.2f * kx;
        float xr =  xv * ct + yv * st;
        float yr = -xv * st + yv * ct;
        float e  = -0.5f * (xr * xr / (pv * pv) + yr * yr / (sv * sv));
        float g  = (av / (2.0f * 3.14159265358979323846f * pv * sv))
                   * __builtin_amdgcn_exp2f(e * 1.44269504088896341f);
        Gt[tap * GTS + u] = f2bf(g);
    }

    // Per-lane nI for this lane's 8 u per K-step (A-operand multipliers), in VGPRs.
    float nIr[4][8];
    {
        const float* nc = nI + c * CN;
        #pragma unroll
        for (int ks = 0; ks < 4; ++ks) {
            const float4* q = (const float4*)(nc + ks * 32 + lg * 8);
            float4 q0 = q[0], q1 = q[1];
            nIr[ks][0] = q0.x; nIr[ks][1] = q0.y; nIr[ks][2] = q0.z; nIr[ks][3] = q0.w;
            nIr[ks][4] = q1.x; nIr[ks][5] = q1.y; nIr[ks][6] = q1.z; nIr[ks][7] = q1.w;
        }
    }

    const float* xc = x   + (size_t)(b * CN + c) * (SN * SN);
    float*       oc = out + (size_t)(b * CN + c) * (SN * SN);
    const float nUc = nU[c];
    const float bn  = __builtin_amdgcn_exp2f(nUc * __builtin_amdgcn_logf(bias[c]));
    const int   c0  = 28 * w;

    __syncthreads();

    // Preload all 12 B-frags (band/block invariant): B[k=u][n=tap] = Gt[tap][u].
    // Lane supplies B[k = ks*32 + lg*8 + j][n = nt*16 + l15].
    sh8 Bf[3][4];
    #pragma unroll
    for (int nt = 0; nt < 3; ++nt)
        #pragma unroll
        for (int ks = 0; ks < 4; ++ks)
            Bf[nt][ks] = *(const sh8*)&Gt[(nt * 16 + l15) * GTS + ks * 32 + lg * 8];

    for (int band = 0; band < 2; ++band) {
        const int r0 = 28 * h + 14 * band;

        // ---- GEMM phase: 40 M-tiles of 16 px (627 valid, rest masked) ----
        for (int mt = wv; mt < 40; mt += 4) {
            int pidx = mt * 16 + l15;              // A-row (px) for this lane
            int prl  = pidx / PCOLS;
            int pcl  = pidx - prl * PCOLS;
            int prow = r0 - 2 + prl;
            int pcol = c0 - 2 + pcl;
            bool vld = ((unsigned)prow < 56u) && ((unsigned)pcol < 56u);
            int off  = vld ? (prow * SN + pcol) : 0;
            float xv = xc[off];
            float L  = vld ? __builtin_amdgcn_logf(xv) : -1e30f;  // OOB -> t=0

            fr4 a0 = {0.f,0.f,0.f,0.f}, a1 = {0.f,0.f,0.f,0.f}, a2 = {0.f,0.f,0.f,0.f};
            #pragma unroll
            for (int ks = 0; ks < 4; ++ks) {
                sh8 af;
                #pragma unroll
                for (int j = 0; j < 8; ++j)
                    af[j] = (short)f2bf(__builtin_amdgcn_exp2f(nIr[ks][j] * L));
                a0 = __builtin_amdgcn_mfma_f32_16x16x32_bf16(af, Bf[0][ks], a0, 0, 0, 0);
                a1 = __builtin_amdgcn_mfma_f32_16x16x32_bf16(af, Bf[1][ks], a1, 0, 0, 0);
                a2 = __builtin_amdgcn_mfma_f32_16x16x32_bf16(af, Bf[2][ks], a2, 0, 0, 0);
            }

            // C layout (m89-verified): row = lg*4 + reg, col = l15.
            #pragma unroll
            for (int nt = 0; nt < 3; ++nt) {
                int tap = nt * 16 + l15;
                fr4 av4 = (nt == 0) ? a0 : ((nt == 1) ? a1 : a2);
                if (tap < PTAP) {
                    #pragma unroll
                    for (int r = 0; r < 4; ++r) {
                        int pi = mt * 16 + lg * 4 + r;
                        if (pi < NPX) {
                            int rw = pi / PCOLS;
                            int cl = pi - rw * PCOLS;
                            Pl[(rw * PCOLS + cl) * PTAP + tap] = f2bf(av4[r]);
                        }
                    }
                }
            }
        }
        __syncthreads();

        // ---- Gather phase: out[y,x] = x^nU / (bias^nU + sum_tap P[shifted, tap]) ----
        #pragma unroll 1
        for (int k = 0; k < 2; ++k) {
            int pp = tid + 256 * k;
            if (pp < 14 * 28) {
                int yl = pp / 28;
                int xl = pp - yl * 28;
                int y  = r0 + yl;
                int xg = c0 + xl;
                float s = 0.0f;
                #pragma unroll
                for (int dy = 0; dy < 6; ++dy) {
                    int base = ((yl + dy) * PCOLS + xl) * PTAP + 6 * dy;
                    #pragma unroll
                    for (int dx = 0; dx < 6; ++dx)
                        s += bf2f(Pl[base + dx * PTAP + dx]);
                }
                float xv  = xc[y * SN + xg];
                float num = __builtin_amdgcn_exp2f(nUc * __builtin_amdgcn_logf(xv));
                oc[y * SN + xg] = num / (bn + s);
            }
        }
        __syncthreads();
    }
}

extern "C" void kernel_launch(void* const* d_in, const int* in_sizes, int n_in,
                              void* d_out, int out_size, void* d_ws, size_t ws_size,
                              hipStream_t stream) {
    const float* x     = (const float*)d_in[0];
    const float* theta = (const float*)d_in[1];
    const float* p     = (const float*)d_in[2];
    const float* sig   = (const float*)d_in[3];
    const float* a     = (const float*)d_in[4];
    const float* nI    = (const float*)d_in[5];
    const float* nU    = (const float*)d_in[6];
    const float* bias  = (const float*)d_in[7];
    float* out = (float*)d_out;

    hipLaunchKernelGGL(divnorm_mfma, dim3(2 * CN * 4), dim3(256), 0, stream,
                       x, theta, p, sig, a, nI, nU, bias, out);
}